// Round 1
// baseline (15240.086 us; speedup 1.0000x reference)
//
#include <hip/hip_runtime.h>
#include <math.h>

#define N_PTS 32768
#define M_SEL 8192
#define K_NBR 64
#define F_IN  64
#define H_MID 128
#define C_OUT 128
#define NCELL 2048      // 16 x 16 x 8 grid, owner-swizzled cell index
#define CAP   192       // per-centroid candidate cap
#define NWF   8         // waves in fps block (one owner per wave)
#define NTF   (NWF * 64)

// ---------- helpers ----------

__device__ __forceinline__ int iclamp(int v, int hi) {
    return v < 0 ? 0 : (v > hi ? hi : v);
}

// owner-swizzled cell id: low bit of (ix,iy,iz) -> owner wave (8 waves),
// so any 3x3x3 spatial neighborhood spreads across all 8 waves.
__device__ __forceinline__ int cell_idx(int ix, int iy, int iz) {
    int w    = (ix & 1) | ((iy & 1) << 1) | ((iz & 1) << 2);
    int rest = ((iz >> 1) * 8 + (iy >> 1)) * 8 + (ix >> 1);      // [0,256)
    return (w << 8) | rest;
}

__device__ __forceinline__ int cell_of(float px, float py, float pz) {
    int ix = iclamp((int)(px * 16.0f), 15);
    int iy = iclamp((int)(py * 16.0f), 15);
    int iz = iclamp((int)(pz * 8.0f), 7);
    return cell_idx(ix, iy, iz);
}

// Bit-exact replica of numpy: ((dx*dx + dy*dy) + dz*dz), rn, no fma.
__device__ __forceinline__ float d2_exact(float ax, float ay, float az,
                                          float bx, float by, float bz) {
#pragma clang fp contract(off)
    float dx = ax - bx, dy = ay - by, dz = az - bz;
    return (dx * dx + dy * dy) + dz * dz;
}

__device__ __forceinline__ unsigned long long umax64(unsigned long long a,
                                                     unsigned long long b) {
    return a > b ? a : b;
}

// pack: [63:32] mind_bits, [29:15] orig^0x7FFF, [14:0] slot.
// Lex order = (mind, -orig); slot never decides (orig unique).
__device__ __forceinline__ unsigned long long make_pk(float nv, unsigned int o,
                                                      unsigned int slot) {
    return ((unsigned long long)__float_as_uint(nv) << 32)
         | ((unsigned long long)((o ^ 0x7FFFu) & 0x7FFFu) << 15)
         | (unsigned long long)slot;
}

// ---------- binning ----------

__global__ void bin_count_kernel(const float* __restrict__ pos, int* __restrict__ cnt) {
    int i = blockIdx.x * blockDim.x + threadIdx.x;
    if (i < N_PTS) {
        atomicAdd(&cnt[cell_of(pos[3*i], pos[3*i+1], pos[3*i+2])], 1);
    }
}

// inclusive Hillis-Steele over 2048 with 1024 threads (2 elements each)
__global__ void scan_kernel(const int* __restrict__ cnt, int* __restrict__ start,
                            int* __restrict__ fill) {
    __shared__ int s[NCELL];
    int t = threadIdx.x;
    int v0 = cnt[t], v1 = cnt[t + 1024];
    s[t] = v0; s[t + 1024] = v1;
    __syncthreads();
    for (int off = 1; off < NCELL; off <<= 1) {
        int a0 = (t >= off) ? s[t - off] : 0;
        int i1 = t + 1024;
        int a1 = (i1 >= off) ? s[i1 - off] : 0;
        __syncthreads();
        s[t] += a0; s[i1] += a1;
        __syncthreads();
    }
    start[t] = s[t] - v0;                fill[t] = s[t] - v0;
    start[t + 1024] = s[t + 1024] - v1;  fill[t + 1024] = s[t + 1024] - v1;
    if (t == 1023) start[NCELL] = s[NCELL - 1];
}

// pq[slot] = (x, y, z, orig_index_as_float_bits)
__global__ void scatter_kernel(const float* __restrict__ pos, int* __restrict__ fill,
                               float4* __restrict__ pq) {
    int i = blockIdx.x * blockDim.x + threadIdx.x;
    if (i < N_PTS) {
        float px = pos[3*i], py = pos[3*i+1], pz = pos[3*i+2];
        int c = cell_of(px, py, pz);
        int slot = atomicAdd(&fill[c], 1);
        pq[slot] = make_float4(px, py, pz, __int_as_float(i));
    }
}

// ---------- FPS ----------
// 512 threads = 8 waves (2/SIMD); wave w OWNS cells [256w,256w+256) and their
// points (wave-private s_mind / s_sub / s_wlist => DS in-order, no barrier
// around them). ONE barrier per iteration, and it is a raw
// "s_waitcnt lgkmcnt(0); s_barrier" — all cross-wave traffic is LDS-only
// (s_gb/s_gbc), so the vmcnt(0) drain __syncthreads would emit is pure loss.
//
// Coords are carried THROUGH the reduction: each lane tracks the xyz of its
// running-max candidate (rmax from touched points; vbx/vby/vbz for cached
// unflagged cell bests). The unique lane whose candidate equals the wave best
// publishes a float4 to s_gbc pre-barrier; phase E selects the winner's coords
// from LDS with a cndmask tournament — the old dependent pq[slot] global load
// (~300-400 cy of L2 latency on the critical path) is gone. The vb coord
// cache is refreshed by pq loads issued right after the barrier, whose latency
// hides under the entire next B phase.
//
// flag_assign: for a lane's 4 cells, ix/iy (hence dx,dy,dxy2) are identical
// across k (rest&7 and (rest>>3)&7 don't depend on k) — computed once.

__global__ __launch_bounds__(NTF) void fps_kernel(
        const float4* __restrict__ pq, const int* __restrict__ cstart,
        const float* __restrict__ pos, int* __restrict__ sel) {
    __shared__ float s_mind[N_PTS];                    // 128 KB (owner-private)
    __shared__ unsigned long long s_sub[NCELL];        // 16 KB (owner-private)
    __shared__ unsigned long long s_redw[NWF][8];      // 512 B (owner-private)
    __shared__ __align__(16) unsigned long long s_gb[2][NWF];  // cross-wave, dbuf
    __shared__ __align__(16) float4 s_gbc[2][NWF];     // cross-wave coords, dbuf
    __shared__ unsigned int s_wlist[NWF][256];         // 8 KB  (owner-private)

    const int tid  = threadIdx.x;
    const int lane = tid & 63;
    const int wid  = tid >> 6;
    const int g    = lane >> 4;     // 16-lane group 0..3
    const int gl   = lane & 15;
    const unsigned long long lmask_lt = (1ULL << lane) - 1ULL;

    for (int i = tid; i < N_PTS; i += NTF) s_mind[i] = INFINITY;
    if (tid == 0) sel[0] = 0;

    // own-cell geometry: ix,iy (and lox,loy) are the same for all 4 k's
    const float lox = (float)(((lane & 7) << 1) | (wid & 1)) * 0.0625f;
    const float loy = (float)((((lane >> 3) & 7) << 1) | ((wid >> 1) & 1)) * 0.0625f;
    float loz[4];
    unsigned int ent[4];
    unsigned long long vb[4];       // per-cell best pk, persistent in registers
    float vbx[4], vby[4], vbz[4];   // coords of per-cell best (valid when vb real)
    bool fmask[4];
    #pragma unroll
    for (int k = 0; k < 4; ++k) {
        const int rest = lane + (k << 6);               // [0,256)
        const int c = (wid << 8) | rest;
        const int iz = (k << 1) | ((wid >> 2) & 1);
        loz[k] = (float)iz * 0.125f;
        const int cs = cstart[c], ce = cstart[c + 1];
        int len = ce - cs; if (len > 511) len = 511;   // statistically impossible
        ent[k] = (unsigned)cs | ((unsigned)len << 15) | ((unsigned)rest << 24);
        // +inf sentinel => every nonempty cell flagged on iteration 1, so the
        // sentinel (garbage coords) never enters the unflagged-vb fold.
        vb[k] = (ce > cs) ? ((0x7F800000ULL << 32) | 0x3FFFFFFFULL) : 0ULL;
        vbx[k] = 0.0f; vby[k] = 0.0f; vbz[k] = 0.0f;
    }

    int nfw = 0;
    float px = pos[0], py = pos[1], pz = pos[2];
    unsigned int sel_reg = 0;       // wave-0 per-lane sel buffer

    auto flag_assign = [&]() {
        float dx = fmaxf(fmaxf(lox - px, px - (lox + 0.0625f)), 0.0f);
        float dy = fmaxf(fmaxf(loy - py, py - (loy + 0.0625f)), 0.0f);
        float dxy2 = dx * dx + dy * dy;
        unsigned int cnt = 0;
        #pragma unroll
        for (int k = 0; k < 4; ++k) {
            const float cm = __uint_as_float((unsigned)(vb[k] >> 32));
            float dz = fmaxf(fmaxf(loz[k] - pz, pz - (loz[k] + 0.125f)), 0.0f);
            float lb2 = fmaf(dz, dz, dxy2);
            bool fl = (lb2 * 0.999f < cm);             // conservative skip bound
            fmask[k] = fl;
            unsigned long long b = __ballot(fl);
            unsigned rank = cnt + (unsigned)__popcll(b & lmask_lt);
            if (fl) s_wlist[wid][rank] = ent[k];
            cnt += (unsigned)__popcll(b);
        }
        nfw = (int)cnt;
    };
    flag_assign();
    __syncthreads();     // covers s_mind init (striped across waves)

    for (int m = 1; m < M_SEL; ++m) {
        // ---- B: own flagged cells, 4 in flight (one per 16-lane group);
        //      per-lane running max (pk + coords) over all touched points ----
        if (lane < 8) s_redw[wid][lane] = 0ULL;
        unsigned long long rmax = 0ULL;
        float rx = 0.0f, ry = 0.0f, rz = 0.0f;
        unsigned e_nxt = (g < nfw) ? s_wlist[wid][g] : 0u;   // 1-ahead prefetch
        for (int i = g; i < nfw; i += 4) {
            const unsigned e = e_nxt;
            if (i + 4 < nfw) e_nxt = s_wlist[wid][i + 4];
            const int cs = (int)(e & 0x7FFFu);
            const int ce = cs + (int)((e >> 15) & 0x1FFu);
            const int c  = (wid << 8) | (int)(e >> 24);
            if (gl == 0) s_sub[c] = 0ULL;              // in-order before atomics
            for (int j = cs + gl; j < ce; j += 16) {
                const float4 q = pq[j];
                const float d2 = d2_exact(q.x, q.y, q.z, px, py, pz);
                const float old = s_mind[j];
                const float nv = d2 < old ? d2 : old;
                s_mind[j] = nv;
                const unsigned long long pk =
                    make_pk(nv, (unsigned)__float_as_int(q.w), (unsigned)j);
                atomicMax(&s_sub[c], pk);              // fire-and-forget
                if (pk > rmax) { rmax = pk; rx = q.x; ry = q.y; rz = q.z; }
            }
        }

        // ---- D: wave best = max(rmax, unflagged vb), coords carried ----
        unsigned long long cand = rmax;
        float cx = rx, cy = ry, cz = rz;
        #pragma unroll
        for (int k = 0; k < 4; ++k)
            if (!fmask[k] && vb[k] > cand) {
                cand = vb[k]; cx = vbx[k]; cy = vby[k]; cz = vbz[k];
            }
        atomicMax(&s_redw[wid][lane & 7], cand);
        unsigned long long best = cand;
        #pragma unroll
        for (int i = 0; i < 8; ++i) best = umax64(best, s_redw[wid][i]);
        // unique owner (pk's are globally unique when nonzero) publishes coords
        if (best == cand && cand != 0ULL)
            s_gbc[m & 1][wid] = make_float4(cx, cy, cz, 0.0f);
        if (lane == 0) s_gb[m & 1][wid] = best;

        // the ONE barrier: LDS-only visibility (no vmcnt drain — all
        // cross-wave traffic is DS; global loads/stores keep flying)
        asm volatile("s_waitcnt lgkmcnt(0)\n\ts_barrier" ::: "memory");

        // ---- refresh vb (+ coord cache) for cells updated this iteration.
        //      s_sub read feeds this iteration's flag_assign (hidden under E);
        //      pq coord load feeds NEXT iteration's fold (hidden under B) ----
        #pragma unroll
        for (int k = 0; k < 4; ++k)
            if (fmask[k]) {
                const unsigned long long v = s_sub[(wid << 8) | (lane + (k << 6))];
                vb[k] = v;
                const float4 q = pq[(unsigned)v & 0x7FFFu];
                vbx[k] = q.x; vby[k] = q.y; vbz[k] = q.z;
            }

        // ---- E: global argmax over 8 wave-bests + coord select (LDS only) ----
        const int mb = m & 1;
        unsigned long long tp[8];
        float tx[8], ty[8], tz[8];
        {
            const ulonglong2* gp = (const ulonglong2*)&s_gb[mb][0];
            const ulonglong2 g0 = gp[0], g1 = gp[1], g2 = gp[2], g3 = gp[3];
            tp[0] = g0.x; tp[1] = g0.y; tp[2] = g1.x; tp[3] = g1.y;
            tp[4] = g2.x; tp[5] = g2.y; tp[6] = g3.x; tp[7] = g3.y;
            #pragma unroll
            for (int i = 0; i < 8; ++i) {
                const float4 q = s_gbc[mb][i];
                tx[i] = q.x; ty[i] = q.y; tz[i] = q.z;
            }
        }
        #pragma unroll
        for (int s = 4; s > 0; s >>= 1) {
            #pragma unroll
            for (int i = 0; i < s; ++i)
                if (tp[i + s] > tp[i]) {
                    tp[i] = tp[i + s]; tx[i] = tx[i + s];
                    ty[i] = ty[i + s]; tz[i] = tz[i + s];
                }
        }
        const unsigned long long gb = tp[0];
        const unsigned orig = (~(unsigned)(gb >> 15)) & 0x7FFFu;

        // buffered sel store: capture in wave-0 lane register; flush 64-wide
        if (wid == 0) {
            if (lane == ((m - 1) & 63)) sel_reg = orig;
            if ((m & 63) == 0) sel[m - 63 + lane] = (int)sel_reg;
        }

        px = tx[0]; py = ty[0]; pz = tz[0];   // exact pq coords, no global load

        // ---- F: own flags + own list for next iteration ----
        flag_assign();
    }
    // tail flush: iterations 8129..8191 live in lanes 0..62
    if (wid == 0 && lane < 63) sel[8129 + lane] = (int)sel_reg;
}

// ---------- ball query: up-to-64 nearest in-radius (one wave / centroid) ----------

__global__ __launch_bounds__(256) void ballq_kernel(
        const float* __restrict__ pos,
        const float4* __restrict__ pq,
        const int* __restrict__ cstart, const int* __restrict__ sel,
        int* __restrict__ nbr, int* __restrict__ ncnt) {
    __shared__ float s_d2[4][CAP];
    __shared__ int   s_o[4][CAP];
    __shared__ int   s_cnt[4];

    const int wid  = threadIdx.x >> 6;
    const int lane = threadIdx.x & 63;
    const int m = blockIdx.x * 4 + wid;

    if (lane == 0) s_cnt[wid] = 0;
    __syncthreads();

    int sidx = sel[m];
    float cx = pos[3*sidx], cy = pos[3*sidx+1], cz = pos[3*sidx+2];
    int ix = iclamp((int)(cx * 16.0f), 15);
    int iy = iclamp((int)(cy * 16.0f), 15);
    int iz = iclamp((int)(cz * 8.0f), 7);
    const float r2 = (float)(0.08 * 0.08);

    // cells reachable within r=0.08: +-2 in x,y (0.0625), +-1 in z (0.125)
    for (int dz = -1; dz <= 1; ++dz) {
        int z = iz + dz; if (z < 0 || z > 7) continue;
        for (int dy = -2; dy <= 2; ++dy) {
            int y = iy + dy; if (y < 0 || y > 15) continue;
            for (int dx = -2; dx <= 2; ++dx) {
                int xx = ix + dx; if (xx < 0 || xx > 15) continue;
                int c = cell_idx(xx, y, z);
                int cs = cstart[c], ce = cstart[c + 1];
                for (int j = cs + lane; j < ce; j += 64) {
                    float4 q = pq[j];
                    float d2 = d2_exact(cx, cy, cz, q.x, q.y, q.z);
                    if (d2 <= r2) {
                        int slot = atomicAdd(&s_cnt[wid], 1);
                        if (slot < CAP) { s_d2[wid][slot] = d2; s_o[wid][slot] = __float_as_int(q.w); }
                    }
                }
            }
        }
    }
    __syncthreads();

    int cnt = s_cnt[wid];
    if (cnt > CAP) cnt = CAP;
    if (cnt <= K_NBR) {
        if (lane < cnt) nbr[m * K_NBR + lane] = s_o[wid][lane];
        if (lane == 0) ncnt[m] = cnt;
    } else {
        // exact (d2, orig-index) lexicographic rank -> keep 64 nearest (matches top_k)
        for (int i = lane; i < cnt; i += 64) {
            float d2 = s_d2[wid][i];
            int   o  = s_o[wid][i];
            int rank = 0;
            for (int j = 0; j < cnt; ++j) {
                float dj = s_d2[wid][j];
                int   oj = s_o[wid][j];
                rank += (dj < d2 || (dj == d2 && oj < o)) ? 1 : 0;
            }
            if (rank < K_NBR) nbr[m * K_NBR + rank] = o;
        }
        if (lane == 0) ncnt[m] = K_NBR;
    }
}

// ---------- PointConv MLP + masked max-pool (fp32, one block / centroid) ----------

__global__ __launch_bounds__(256) void mlp_kernel(
        const float* __restrict__ x, const float* __restrict__ pos,
        const float* __restrict__ W1, const float* __restrict__ b1,
        const float* __restrict__ W2, const float* __restrict__ b2,
        const int* __restrict__ sel, const int* __restrict__ nbr,
        const int* __restrict__ ncnt, float* __restrict__ out) {
    __shared__ __align__(16) float feat[64][68];   // 67 used + pad
    __shared__ __align__(16) float h[64][H_MID];
    __shared__ float part[2][H_MID];

    const int m = blockIdx.x;
    const int tid = threadIdx.x;
    const int cnt = ncnt[m];
    const int s = sel[m];
    float cx = pos[3*s], cy = pos[3*s+1], cz = pos[3*s+2];

    for (int i = tid; i < 64 * 68; i += 256) ((float*)feat)[i] = 0.0f;
    __syncthreads();

    for (int i = tid; i < cnt * F_IN; i += 256) {
        int k = i >> 6, f = i & 63;
        int j = nbr[m * K_NBR + k];
        feat[k][f] = x[(size_t)j * F_IN + f];
    }
    if (tid < 64 && tid < cnt) {
        int j = nbr[m * K_NBR + tid];
        feat[tid][64] = pos[3*j]     - cx;
        feat[tid][65] = pos[3*j + 1] - cy;
        feat[tid][66] = pos[3*j + 2] - cz;
    }
    __syncthreads();

    const int c = tid & 127;
    const int half = tid >> 7;

    for (int k = half; k < 64; k += 2) {
        float acc = b1[c];
        const float4* fr = (const float4*)&feat[k][0];
#pragma unroll
        for (int f4 = 0; f4 < 16; ++f4) {
            float4 fv = fr[f4];
            int fb = f4 * 4;
            acc = fmaf(fv.x, W1[(fb    ) * H_MID + c], acc);
            acc = fmaf(fv.y, W1[(fb + 1) * H_MID + c], acc);
            acc = fmaf(fv.z, W1[(fb + 2) * H_MID + c], acc);
            acc = fmaf(fv.w, W1[(fb + 3) * H_MID + c], acc);
        }
        acc = fmaf(feat[k][64], W1[64 * H_MID + c], acc);
        acc = fmaf(feat[k][65], W1[65 * H_MID + c], acc);
        acc = fmaf(feat[k][66], W1[66 * H_MID + c], acc);
        h[k][c] = fmaxf(acc, 0.0f);
    }
    __syncthreads();

    float best = -INFINITY;
    for (int k = half; k < cnt; k += 2) {
        float acc = 0.0f;
        const float4* hr = (const float4*)&h[k][0];
#pragma unroll
        for (int q = 0; q < 32; ++q) {
            float4 hv = hr[q];
            int hb = q * 4;
            acc = fmaf(hv.x, W2[(hb    ) * C_OUT + c], acc);
            acc = fmaf(hv.y, W2[(hb + 1) * C_OUT + c], acc);
            acc = fmaf(hv.z, W2[(hb + 2) * C_OUT + c], acc);
            acc = fmaf(hv.w, W2[(hb + 3) * C_OUT + c], acc);
        }
        best = fmaxf(best, acc);
    }
    part[half][c] = best;
    __syncthreads();
    if (tid < 128) {
        out[(size_t)m * C_OUT + tid] = fmaxf(part[0][tid], part[1][tid]) + b2[tid];
    }
}

// ---------- outputs 2 & 3 ----------

__global__ void tail_kernel(const float* __restrict__ pos, const int* __restrict__ sel,
                            float* __restrict__ out_selpos, float* __restrict__ out_batch) {
    int i = blockIdx.x * blockDim.x + threadIdx.x;
    if (i < M_SEL) {
        int s = sel[i];
        out_selpos[3*i]     = pos[3*s];
        out_selpos[3*i + 1] = pos[3*s + 1];
        out_selpos[3*i + 2] = pos[3*s + 2];
        out_batch[i] = 0.0f;
    }
}

// ---------- launch ----------

extern "C" void kernel_launch(void* const* d_in, const int* in_sizes, int n_in,
                              void* d_out, int out_size, void* d_ws, size_t ws_size,
                              hipStream_t stream) {
    const float* x   = (const float*)d_in[0];
    const float* pos = (const float*)d_in[1];
    // d_in[2] = batch (int64, all zeros) — unused
    const float* W1 = (const float*)d_in[3];
    const float* b1 = (const float*)d_in[4];
    const float* W2 = (const float*)d_in[5];
    const float* b2 = (const float*)d_in[6];

    float* out        = (float*)d_out;
    float* out_selpos = out + (size_t)M_SEL * C_OUT;
    float* out_batch  = out_selpos + (size_t)M_SEL * 3;

    char* ws = (char*)d_ws;
    size_t off = 0;
    auto alloc = [&](size_t bytes) -> void* {
        void* p = ws + off;
        off = (off + bytes + 255) & ~(size_t)255;
        return p;
    };
    int*    cnt    = (int*)alloc(NCELL * 4);
    int*    cstart = (int*)alloc((NCELL + 1) * 4);
    int*    cfill  = (int*)alloc(NCELL * 4);
    float4* pq     = (float4*)alloc((size_t)N_PTS * 16);
    int*    sel    = (int*)alloc(M_SEL * 4);
    int*    nbr    = (int*)alloc((size_t)M_SEL * K_NBR * 4);
    int*    ncnt   = (int*)alloc(M_SEL * 4);
    (void)ws_size; (void)in_sizes; (void)n_in; (void)out_size;

    (void)hipMemsetAsync(cnt, 0, NCELL * 4, stream);
    bin_count_kernel<<<N_PTS / 256, 256, 0, stream>>>(pos, cnt);
    scan_kernel<<<1, 1024, 0, stream>>>(cnt, cstart, cfill);
    scatter_kernel<<<N_PTS / 256, 256, 0, stream>>>(pos, cfill, pq);
    fps_kernel<<<1, NTF, 0, stream>>>(pq, cstart, pos, sel);
    ballq_kernel<<<M_SEL / 4, 256, 0, stream>>>(pos, pq, cstart, sel, nbr, ncnt);
    mlp_kernel<<<M_SEL, 256, 0, stream>>>(x, pos, W1, b1, W2, b2, sel, nbr, ncnt, out);
    tail_kernel<<<(M_SEL + 255) / 256, 256, 0, stream>>>(pos, sel, out_selpos, out_batch);
}

// Round 2
// 11908.781 us; speedup vs baseline: 1.2797x; 1.2797x over previous
//
#include <hip/hip_runtime.h>
#include <math.h>

#define N_PTS 32768
#define M_SEL 8192
#define K_NBR 64
#define F_IN  64
#define H_MID 128
#define C_OUT 128
#define NCELL 2048      // 16 x 16 x 8 grid, owner-swizzled cell index
#define CAP   192       // per-centroid candidate cap
#define NWF   8         // waves in fps block (one owner per wave)
#define NTF   (NWF * 64)

// ---------- helpers ----------

__device__ __forceinline__ int iclamp(int v, int hi) {
    return v < 0 ? 0 : (v > hi ? hi : v);
}

// owner-swizzled cell id: low bit of (ix,iy,iz) -> owner wave (8 waves),
// so any 3x3x3 spatial neighborhood spreads across all 8 waves.
__device__ __forceinline__ int cell_idx(int ix, int iy, int iz) {
    int w    = (ix & 1) | ((iy & 1) << 1) | ((iz & 1) << 2);
    int rest = ((iz >> 1) * 8 + (iy >> 1)) * 8 + (ix >> 1);      // [0,256)
    return (w << 8) | rest;
}

__device__ __forceinline__ int cell_of(float px, float py, float pz) {
    int ix = iclamp((int)(px * 16.0f), 15);
    int iy = iclamp((int)(py * 16.0f), 15);
    int iz = iclamp((int)(pz * 8.0f), 7);
    return cell_idx(ix, iy, iz);
}

// Bit-exact replica of numpy: ((dx*dx + dy*dy) + dz*dz), rn, no fma.
__device__ __forceinline__ float d2_exact(float ax, float ay, float az,
                                          float bx, float by, float bz) {
#pragma clang fp contract(off)
    float dx = ax - bx, dy = ay - by, dz = az - bz;
    return (dx * dx + dy * dy) + dz * dz;
}

__device__ __forceinline__ unsigned long long umax64(unsigned long long a,
                                                     unsigned long long b) {
    return a > b ? a : b;
}

// ---------- binning ----------

__global__ void bin_count_kernel(const float* __restrict__ pos, int* __restrict__ cnt) {
    int i = blockIdx.x * blockDim.x + threadIdx.x;
    if (i < N_PTS) {
        atomicAdd(&cnt[cell_of(pos[3*i], pos[3*i+1], pos[3*i+2])], 1);
    }
}

// inclusive Hillis-Steele over 2048 with 1024 threads (2 elements each)
__global__ void scan_kernel(const int* __restrict__ cnt, int* __restrict__ start,
                            int* __restrict__ fill) {
    __shared__ int s[NCELL];
    int t = threadIdx.x;
    int v0 = cnt[t], v1 = cnt[t + 1024];
    s[t] = v0; s[t + 1024] = v1;
    __syncthreads();
    for (int off = 1; off < NCELL; off <<= 1) {
        int a0 = (t >= off) ? s[t - off] : 0;
        int i1 = t + 1024;
        int a1 = (i1 >= off) ? s[i1 - off] : 0;
        __syncthreads();
        s[t] += a0; s[i1] += a1;
        __syncthreads();
    }
    start[t] = s[t] - v0;                fill[t] = s[t] - v0;
    start[t + 1024] = s[t + 1024] - v1;  fill[t + 1024] = s[t + 1024] - v1;
    if (t == 1023) start[NCELL] = s[NCELL - 1];
}

// pq[slot] = (x, y, z, packed_lo_bits) where
// lo = ((orig ^ 0x7FFF) & 0x7FFF) << 15 | slot  — the low word of the FPS pk,
// precomputed here so the fps inner loop builds pk with ZERO VALU ops.
__global__ void scatter_kernel(const float* __restrict__ pos, int* __restrict__ fill,
                               float4* __restrict__ pq) {
    int i = blockIdx.x * blockDim.x + threadIdx.x;
    if (i < N_PTS) {
        float px = pos[3*i], py = pos[3*i+1], pz = pos[3*i+2];
        int c = cell_of(px, py, pz);
        int slot = atomicAdd(&fill[c], 1);
        unsigned lo = (((unsigned)i ^ 0x7FFFu) & 0x7FFFu) << 15 | (unsigned)slot;
        pq[slot] = make_float4(px, py, pz, __uint_as_float(lo));
    }
}

// ---------- FPS ----------
// 512 threads = 8 waves (2/SIMD); wave w OWNS cells [256w,256w+256) and their
// points (wave-private s_mind / s_sub / s_wlist => DS in-order, no barrier
// around them). ONE barrier per iteration, raw "s_waitcnt lgkmcnt(0);
// s_barrier" — all cross-wave traffic (s_gb) is LDS-only, so the vmcnt(0)
// drain __syncthreads would emit is pure loss.
//
// pack: [63:32] mind_bits, [29:15] orig^0x7FFF, [14:0] slot.
// Lex order = (mind, -orig); slot never decides (orig unique).
// The low 32 bits are PRECOMPUTED into pq.w by scatter_kernel.
//
// Post-barrier order matters: E (argmax over the 8 wave-bests) runs FIRST so
// the dependent pq[slot] broadcast load issues as early as possible; the
// s_sub->vb refresh and sel bookkeeping then execute under that load's
// latency. (Round-1 lesson: this kernel is serial-chain-bound — carrying
// coords through the reduction to kill this load added MORE chain VALU than
// the load costs. Keep reductions slim.)

__global__ __launch_bounds__(NTF) void fps_kernel(
        const float4* __restrict__ pq, const int* __restrict__ cstart,
        const float* __restrict__ pos, int* __restrict__ sel) {
    __shared__ float s_mind[N_PTS];                    // 128 KB (owner-private)
    __shared__ unsigned long long s_sub[NCELL];        // 16 KB (owner-private)
    __shared__ unsigned long long s_redw[NWF][8];      // 512 B (owner-private)
    __shared__ __align__(16) unsigned long long s_gb[2][NWF];  // cross-wave, dbuf
    __shared__ unsigned int s_wlist[NWF][256];         // 8 KB  (owner-private)

    const int tid  = threadIdx.x;
    const int lane = tid & 63;
    const int wid  = tid >> 6;
    const int g    = lane >> 4;     // 16-lane group 0..3
    const int gl   = lane & 15;
    const unsigned long long lmask_lt = (1ULL << lane) - 1ULL;

    for (int i = tid; i < N_PTS; i += NTF) s_mind[i] = INFINITY;
    if (tid == 0) sel[0] = 0;

    // own-cell geometry: ix,iy (hence lox,loy) are identical across a lane's
    // 4 cells (k only changes iz) — hoisted out of flag_assign.
    const float lox = (float)(((lane & 7) << 1) | (wid & 1)) * 0.0625f;
    const float loy = (float)((((lane >> 3) & 7) << 1) | ((wid >> 1) & 1)) * 0.0625f;
    float loz[4];
    unsigned int ent[4];
    unsigned long long vb[4];       // per-cell best pk, persistent in registers
    bool fmask[4];
    #pragma unroll
    for (int k = 0; k < 4; ++k) {
        const int rest = lane + (k << 6);               // [0,256)
        const int c = (wid << 8) | rest;
        const int iz = (k << 1) | ((wid >> 2) & 1);
        loz[k] = (float)iz * 0.125f;
        const int cs = cstart[c], ce = cstart[c + 1];
        int len = ce - cs; if (len > 511) len = 511;   // statistically impossible
        ent[k] = (unsigned)cs | ((unsigned)len << 15) | ((unsigned)rest << 24);
        // +inf sentinel => every nonempty cell flagged on iteration 1
        vb[k] = (ce > cs) ? ((0x7F800000ULL << 32) | 0x3FFFFFFFULL) : 0ULL;
    }

    int nfw = 0;
    float px = pos[0], py = pos[1], pz = pos[2];
    unsigned int sel_reg = 0;       // wave-0 per-lane sel buffer

    auto flag_assign = [&]() {
        float dx = fmaxf(fmaxf(lox - px, px - (lox + 0.0625f)), 0.0f);
        float dy = fmaxf(fmaxf(loy - py, py - (loy + 0.0625f)), 0.0f);
        float dxy2 = dx * dx + dy * dy;
        unsigned int cnt = 0;
        #pragma unroll
        for (int k = 0; k < 4; ++k) {
            const float cm = __uint_as_float((unsigned)(vb[k] >> 32));
            float dz = fmaxf(fmaxf(loz[k] - pz, pz - (loz[k] + 0.125f)), 0.0f);
            float lb2 = fmaf(dz, dz, dxy2);
            bool fl = (lb2 * 0.999f < cm);             // conservative skip bound
            fmask[k] = fl;
            unsigned long long b = __ballot(fl);
            unsigned rank = cnt + (unsigned)__popcll(b & lmask_lt);
            if (fl) s_wlist[wid][rank] = ent[k];
            cnt += (unsigned)__popcll(b);
        }
        nfw = (int)cnt;
    };
    flag_assign();
    __syncthreads();     // covers s_mind init (striped across waves)

    for (int m = 1; m < M_SEL; ++m) {
        // ---- B: own flagged cells, 4 in flight (one per 16-lane group);
        //      rmax = per-lane running max over all touched points ----
        if (lane < 8) s_redw[wid][lane] = 0ULL;
        unsigned long long rmax = 0ULL;
        unsigned e_nxt = (g < nfw) ? s_wlist[wid][g] : 0u;   // 1-ahead prefetch
        for (int i = g; i < nfw; i += 4) {
            const unsigned e = e_nxt;
            if (i + 4 < nfw) e_nxt = s_wlist[wid][i + 4];
            const int cs = (int)(e & 0x7FFFu);
            const int ce = cs + (int)((e >> 15) & 0x1FFu);
            const int c  = (wid << 8) | (int)(e >> 24);
            if (gl == 0) s_sub[c] = 0ULL;              // in-order before atomics
            for (int j = cs + gl; j < ce; j += 16) {
                const float4 q = pq[j];
                const float d2 = d2_exact(q.x, q.y, q.z, px, py, pz);
                const float nv = fminf(d2, s_mind[j]);
                s_mind[j] = nv;
                const unsigned long long pk =
                    ((unsigned long long)__float_as_uint(nv) << 32)
                  | (unsigned long long)__float_as_uint(q.w);
                atomicMax(&s_sub[c], pk);              // fire-and-forget
                rmax = umax64(rmax, pk);
            }
        }

        // ---- D: wave best = max(rmax, unflagged vb) — NO s_sub readback ----
        unsigned long long best = rmax;
        #pragma unroll
        for (int k = 0; k < 4; ++k)
            if (!fmask[k]) best = umax64(best, vb[k]);
        atomicMax(&s_redw[wid][lane & 7], best);
        #pragma unroll
        for (int i = 0; i < 8; ++i) best = umax64(best, s_redw[wid][i]);
        if (lane == 0) s_gb[m & 1][wid] = best;

        // the ONE barrier: LDS-only visibility (no vmcnt drain — global
        // loads/stores keep flying across it)
        asm volatile("s_waitcnt lgkmcnt(0)\n\ts_barrier" ::: "memory");

        // ---- E FIRST: global argmax over 8 wave-bests (4 x b128 + max tree),
        //      so the dependent pq[slot] load issues as early as possible ----
        const ulonglong2* gp = (const ulonglong2*)&s_gb[m & 1][0];
        const ulonglong2 g0 = gp[0], g1 = gp[1], g2 = gp[2], g3 = gp[3];
        unsigned long long gb = umax64(
            umax64(umax64(g0.x, g0.y), umax64(g1.x, g1.y)),
            umax64(umax64(g2.x, g2.y), umax64(g3.x, g3.y)));
        const unsigned orig = (~(unsigned)(gb >> 15)) & 0x7FFFu;
        const unsigned slot = (unsigned)gb & 0x7FFFu;
        const float4 qp = pq[slot];                    // L1/L2-hot broadcast

        // ---- refresh vb for cells updated this iteration (s_sub reads and
        //      sel bookkeeping hide under the pq[slot] load latency) ----
        #pragma unroll
        for (int k = 0; k < 4; ++k)
            if (fmask[k]) vb[k] = s_sub[(wid << 8) | (lane + (k << 6))];

        // buffered sel store: capture in wave-0 lane register; flush 64-wide
        if (wid == 0) {
            if (lane == ((m - 1) & 63)) sel_reg = orig;
            if ((m & 63) == 0) sel[m - 63 + lane] = (int)sel_reg;
        }

        px = qp.x; py = qp.y; pz = qp.z;

        // ---- F: own flags + own list for next iteration ----
        flag_assign();
    }
    // tail flush: iterations 8129..8191 live in lanes 0..62
    if (wid == 0 && lane < 63) sel[8129 + lane] = (int)sel_reg;
}

// ---------- ball query: up-to-64 nearest in-radius (one wave / centroid) ----------

__global__ __launch_bounds__(256) void ballq_kernel(
        const float* __restrict__ pos,
        const float4* __restrict__ pq,
        const int* __restrict__ cstart, const int* __restrict__ sel,
        int* __restrict__ nbr, int* __restrict__ ncnt) {
    __shared__ float s_d2[4][CAP];
    __shared__ int   s_o[4][CAP];
    __shared__ int   s_cnt[4];

    const int wid  = threadIdx.x >> 6;
    const int lane = threadIdx.x & 63;
    const int m = blockIdx.x * 4 + wid;

    if (lane == 0) s_cnt[wid] = 0;
    __syncthreads();

    int sidx = sel[m];
    float cx = pos[3*sidx], cy = pos[3*sidx+1], cz = pos[3*sidx+2];
    int ix = iclamp((int)(cx * 16.0f), 15);
    int iy = iclamp((int)(cy * 16.0f), 15);
    int iz = iclamp((int)(cz * 8.0f), 7);
    const float r2 = (float)(0.08 * 0.08);

    // cells reachable within r=0.08: +-2 in x,y (0.0625), +-1 in z (0.125)
    for (int dz = -1; dz <= 1; ++dz) {
        int z = iz + dz; if (z < 0 || z > 7) continue;
        for (int dy = -2; dy <= 2; ++dy) {
            int y = iy + dy; if (y < 0 || y > 15) continue;
            for (int dx = -2; dx <= 2; ++dx) {
                int xx = ix + dx; if (xx < 0 || xx > 15) continue;
                int c = cell_idx(xx, y, z);
                int cs = cstart[c], ce = cstart[c + 1];
                for (int j = cs + lane; j < ce; j += 64) {
                    float4 q = pq[j];
                    float d2 = d2_exact(cx, cy, cz, q.x, q.y, q.z);
                    if (d2 <= r2) {
                        int slot = atomicAdd(&s_cnt[wid], 1);
                        if (slot < CAP) {
                            // unpack orig index from the pk low word in q.w
                            unsigned lo = __float_as_uint(q.w);
                            int orig = (int)(((lo >> 15) & 0x7FFFu) ^ 0x7FFFu);
                            s_d2[wid][slot] = d2; s_o[wid][slot] = orig;
                        }
                    }
                }
            }
        }
    }
    __syncthreads();

    int cnt = s_cnt[wid];
    if (cnt > CAP) cnt = CAP;
    if (cnt <= K_NBR) {
        if (lane < cnt) nbr[m * K_NBR + lane] = s_o[wid][lane];
        if (lane == 0) ncnt[m] = cnt;
    } else {
        // exact (d2, orig-index) lexicographic rank -> keep 64 nearest (matches top_k)
        for (int i = lane; i < cnt; i += 64) {
            float d2 = s_d2[wid][i];
            int   o  = s_o[wid][i];
            int rank = 0;
            for (int j = 0; j < cnt; ++j) {
                float dj = s_d2[wid][j];
                int   oj = s_o[wid][j];
                rank += (dj < d2 || (dj == d2 && oj < o)) ? 1 : 0;
            }
            if (rank < K_NBR) nbr[m * K_NBR + rank] = o;
        }
        if (lane == 0) ncnt[m] = K_NBR;
    }
}

// ---------- PointConv MLP + masked max-pool (fp32, one block / centroid) ----------

__global__ __launch_bounds__(256) void mlp_kernel(
        const float* __restrict__ x, const float* __restrict__ pos,
        const float* __restrict__ W1, const float* __restrict__ b1,
        const float* __restrict__ W2, const float* __restrict__ b2,
        const int* __restrict__ sel, const int* __restrict__ nbr,
        const int* __restrict__ ncnt, float* __restrict__ out) {
    __shared__ __align__(16) float feat[64][68];   // 67 used + pad
    __shared__ __align__(16) float h[64][H_MID];
    __shared__ float part[2][H_MID];

    const int m = blockIdx.x;
    const int tid = threadIdx.x;
    const int cnt = ncnt[m];
    const int s = sel[m];
    float cx = pos[3*s], cy = pos[3*s+1], cz = pos[3*s+2];

    for (int i = tid; i < 64 * 68; i += 256) ((float*)feat)[i] = 0.0f;
    __syncthreads();

    for (int i = tid; i < cnt * F_IN; i += 256) {
        int k = i >> 6, f = i & 63;
        int j = nbr[m * K_NBR + k];
        feat[k][f] = x[(size_t)j * F_IN + f];
    }
    if (tid < 64 && tid < cnt) {
        int j = nbr[m * K_NBR + tid];
        feat[tid][64] = pos[3*j]     - cx;
        feat[tid][65] = pos[3*j + 1] - cy;
        feat[tid][66] = pos[3*j + 2] - cz;
    }
    __syncthreads();

    const int c = tid & 127;
    const int half = tid >> 7;

    for (int k = half; k < 64; k += 2) {
        float acc = b1[c];
        const float4* fr = (const float4*)&feat[k][0];
#pragma unroll
        for (int f4 = 0; f4 < 16; ++f4) {
            float4 fv = fr[f4];
            int fb = f4 * 4;
            acc = fmaf(fv.x, W1[(fb    ) * H_MID + c], acc);
            acc = fmaf(fv.y, W1[(fb + 1) * H_MID + c], acc);
            acc = fmaf(fv.z, W1[(fb + 2) * H_MID + c], acc);
            acc = fmaf(fv.w, W1[(fb + 3) * H_MID + c], acc);
        }
        acc = fmaf(feat[k][64], W1[64 * H_MID + c], acc);
        acc = fmaf(feat[k][65], W1[65 * H_MID + c], acc);
        acc = fmaf(feat[k][66], W1[66 * H_MID + c], acc);
        h[k][c] = fmaxf(acc, 0.0f);
    }
    __syncthreads();

    float best = -INFINITY;
    for (int k = half; k < cnt; k += 2) {
        float acc = 0.0f;
        const float4* hr = (const float4*)&h[k][0];
#pragma unroll
        for (int q = 0; q < 32; ++q) {
            float4 hv = hr[q];
            int hb = q * 4;
            acc = fmaf(hv.x, W2[(hb    ) * C_OUT + c], acc);
            acc = fmaf(hv.y, W2[(hb + 1) * C_OUT + c], acc);
            acc = fmaf(hv.z, W2[(hb + 2) * C_OUT + c], acc);
            acc = fmaf(hv.w, W2[(hb + 3) * C_OUT + c], acc);
        }
        best = fmaxf(best, acc);
    }
    part[half][c] = best;
    __syncthreads();
    if (tid < 128) {
        out[(size_t)m * C_OUT + tid] = fmaxf(part[0][tid], part[1][tid]) + b2[tid];
    }
}

// ---------- outputs 2 & 3 ----------

__global__ void tail_kernel(const float* __restrict__ pos, const int* __restrict__ sel,
                            float* __restrict__ out_selpos, float* __restrict__ out_batch) {
    int i = blockIdx.x * blockDim.x + threadIdx.x;
    if (i < M_SEL) {
        int s = sel[i];
        out_selpos[3*i]     = pos[3*s];
        out_selpos[3*i + 1] = pos[3*s + 1];
        out_selpos[3*i + 2] = pos[3*s + 2];
        out_batch[i] = 0.0f;
    }
}

// ---------- launch ----------

extern "C" void kernel_launch(void* const* d_in, const int* in_sizes, int n_in,
                              void* d_out, int out_size, void* d_ws, size_t ws_size,
                              hipStream_t stream) {
    const float* x   = (const float*)d_in[0];
    const float* pos = (const float*)d_in[1];
    // d_in[2] = batch (int64, all zeros) — unused
    const float* W1 = (const float*)d_in[3];
    const float* b1 = (const float*)d_in[4];
    const float* W2 = (const float*)d_in[5];
    const float* b2 = (const float*)d_in[6];

    float* out        = (float*)d_out;
    float* out_selpos = out + (size_t)M_SEL * C_OUT;
    float* out_batch  = out_selpos + (size_t)M_SEL * 3;

    char* ws = (char*)d_ws;
    size_t off = 0;
    auto alloc = [&](size_t bytes) -> void* {
        void* p = ws + off;
        off = (off + bytes + 255) & ~(size_t)255;
        return p;
    };
    int*    cnt    = (int*)alloc(NCELL * 4);
    int*    cstart = (int*)alloc((NCELL + 1) * 4);
    int*    cfill  = (int*)alloc(NCELL * 4);
    float4* pq     = (float4*)alloc((size_t)N_PTS * 16);
    int*    sel    = (int*)alloc(M_SEL * 4);
    int*    nbr    = (int*)alloc((size_t)M_SEL * K_NBR * 4);
    int*    ncnt   = (int*)alloc(M_SEL * 4);
    (void)ws_size; (void)in_sizes; (void)n_in; (void)out_size;

    (void)hipMemsetAsync(cnt, 0, NCELL * 4, stream);
    bin_count_kernel<<<N_PTS / 256, 256, 0, stream>>>(pos, cnt);
    scan_kernel<<<1, 1024, 0, stream>>>(cnt, cstart, cfill);
    scatter_kernel<<<N_PTS / 256, 256, 0, stream>>>(pos, cfill, pq);
    fps_kernel<<<1, NTF, 0, stream>>>(pq, cstart, pos, sel);
    ballq_kernel<<<M_SEL / 4, 256, 0, stream>>>(pos, pq, cstart, sel, nbr, ncnt);
    mlp_kernel<<<M_SEL, 256, 0, stream>>>(x, pos, W1, b1, W2, b2, sel, nbr, ncnt, out);
    tail_kernel<<<(M_SEL + 255) / 256, 256, 0, stream>>>(pos, sel, out_selpos, out_batch);
}